// Round 10
// baseline (1477.398 us; speedup 1.0000x reference)
//
#include <hip/hip_runtime.h>
#include <hip/hip_bf16.h>

#define N_NODESC 100000
#define N_EDGESC 250000
#define EMB 300
#define LD 304      // fp32 h stride (float4-friendly)
#define LD4 76
#define LAYERS 5
#define BN_EPS 1e-5f

#define K1 320      // padded K for GEMM1 (agg stride)
#define N1 640      // padded N for GEMM1 (hmid stride, = K for GEMM2)
#define K2 640
#define N2 384      // padded N for GEMM2 (output guarded to 300)

#define NB_SCAN 391 // ceil(100000/256)

typedef __attribute__((ext_vector_type(8))) short short8;
typedef __attribute__((ext_vector_type(4))) float f32x4;

#define GLOAD16(g, l) __builtin_amdgcn_global_load_lds( \
    (const __attribute__((address_space(1))) void*)(g), \
    (__attribute__((address_space(3))) void*)(l), 16, 0, 0)

__device__ __forceinline__ float4 f4add(float4 a, float4 b){
    return make_float4(a.x+b.x, a.y+b.y, a.z+b.z, a.w+b.w);
}
__device__ __forceinline__ unsigned short f2bf(float f){
    __hip_bfloat16 h = __float2bfloat16(f);
    return *(unsigned short*)&h;
}

// ---------------- utility zero kernels --------------------------------------
__global__ void k_zero_i(int* p, int n){
    int i = blockIdx.x*blockDim.x + threadIdx.x;
    if(i < n) p[i] = 0;
}
__global__ void k_zero_f(float* p, int n){
    int i = blockIdx.x*blockDim.x + threadIdx.x;
    if(i < n) p[i] = 0.f;
}

// ---------------- atom encoder: h = emb1[x0] + emb2[x1], fp32 stride LD -----
__global__ void k_atom(const int* __restrict__ x,
                       const float* __restrict__ e1,
                       const float* __restrict__ e2,
                       float* __restrict__ h){
    int idx = blockIdx.x*blockDim.x + threadIdx.x;
    if(idx >= N_NODESC*LD4) return;
    int i = idx / LD4, c = idx % LD4;
    float4 v = make_float4(0,0,0,0);
    if(c < 75){
        int i0 = x[2*i], i1 = x[2*i+1];
        const float4* r1 = (const float4*)(e1 + (size_t)i0*EMB);
        const float4* r2 = (const float4*)(e2 + (size_t)i1*EMB);
        v = f4add(r1[c], r2[c]);
    }
    ((float4*)h)[idx] = v;
}

// ---------------- combined edge-embedding table etab[l][ea0*3+ea1][LD] ------
__global__ void k_etab(const float* __restrict__ e1,
                       const float* __restrict__ e2,
                       float* __restrict__ etab){
    int idx = blockIdx.x*blockDim.x + threadIdx.x;
    if(idx >= LAYERS*18*LD4) return;
    int l = idx / (18*LD4);
    int r = idx % (18*LD4);
    int c = r / LD4, f = r % LD4;
    float4 v = make_float4(0,0,0,0);
    if(f < 75){
        const float4* r1 = (const float4*)(e1 + (size_t)(l*6 + c/3)*EMB);
        const float4* r2 = (const float4*)(e2 + (size_t)(l*3 + c%3)*EMB);
        v = f4add(r1[f], r2[f]);
    }
    ((float4*)etab)[idx] = v;
}

// ---------------- weight prep: B^T padded bf16 ------------------------------
__global__ void k_prepw1(const float* __restrict__ W1, unsigned short* __restrict__ wb){
    int idx = blockIdx.x*blockDim.x + threadIdx.x;
    if(idx >= LAYERS*N1*K1) return;
    int l = idx / (N1*K1);
    int r = idx % (N1*K1);
    int n = r / K1, k = r % K1;
    float v = (n < 600 && k < EMB) ? W1[((size_t)l*EMB + k)*600 + n] : 0.f;
    wb[idx] = f2bf(v);
}
__global__ void k_prepw2(const float* __restrict__ W2, unsigned short* __restrict__ wb){
    int idx = blockIdx.x*blockDim.x + threadIdx.x;
    if(idx >= LAYERS*N2*K2) return;
    int l = idx / (N2*K2);
    int r = idx % (N2*K2);
    int n = r / K2, k = r % K2;
    float v = (n < EMB && k < 600) ? W2[((size_t)l*600 + k)*EMB + n] : 0.f;
    wb[idx] = f2bf(v);
}
__global__ void k_prepb1(const float* __restrict__ b1, float* __restrict__ bp){
    int idx = blockIdx.x*blockDim.x + threadIdx.x;
    if(idx >= LAYERS*N1) return;
    int l = idx / N1, n = idx % N1;
    bp[idx] = (n < 600) ? b1[(size_t)l*600 + n] : 0.f;
}

// ---------------- CSR build -------------------------------------------------
__global__ void k_deg(const int* __restrict__ ei, int* __restrict__ deg){
    int e = blockIdx.x*blockDim.x + threadIdx.x;
    if(e >= N_EDGESC) return;
    atomicAdd(&deg[ei[N_EDGESC + e]], 1);
}

__global__ void k_bsum(const int* __restrict__ deg, int* __restrict__ bsum){
    int g = blockIdx.x*256 + threadIdx.x;
    int v = (g < N_NODESC) ? deg[g] : 0;
    #pragma unroll
    for(int o=32;o>0;o>>=1) v += __shfl_down(v, o);
    __shared__ int sw[4];
    if((threadIdx.x & 63) == 0) sw[threadIdx.x>>6] = v;
    __syncthreads();
    if(threadIdx.x == 0) bsum[blockIdx.x] = sw[0]+sw[1]+sw[2]+sw[3];
}

__global__ void k_bscan(const int* __restrict__ bsum, int* __restrict__ bpre,
                        int* __restrict__ offs){
    __shared__ int sh[512];
    int t = threadIdx.x;
    int v = (t < NB_SCAN) ? bsum[t] : 0;
    sh[t] = v; __syncthreads();
    for(int o=1;o<512;o<<=1){
        int u = (t >= o) ? sh[t-o] : 0;
        __syncthreads();
        sh[t] += u;
        __syncthreads();
    }
    if(t < NB_SCAN) bpre[t] = sh[t] - v;
    if(t == NB_SCAN-1) offs[N_NODESC] = sh[t];
}

__global__ void k_offs(const int* __restrict__ deg, const int* __restrict__ bpre,
                       int* __restrict__ offs, int* __restrict__ cursor){
    __shared__ int sh[256];
    int t = threadIdx.x;
    int g = blockIdx.x*256 + t;
    int v = (g < N_NODESC) ? deg[g] : 0;
    sh[t] = v; __syncthreads();
    for(int o=1;o<256;o<<=1){
        int u = (t >= o) ? sh[t-o] : 0;
        __syncthreads();
        sh[t] += u;
        __syncthreads();
    }
    if(g < N_NODESC){
        int e = bpre[blockIdx.x] + sh[t] - v;
        offs[g] = e; cursor[g] = e;
    }
}

__global__ void k_fill(const int* __restrict__ ei, const int* __restrict__ ea,
                       int* __restrict__ cursor,
                       int* __restrict__ csr_src, int* __restrict__ csr_ea){
    int e = blockIdx.x*blockDim.x + threadIdx.x;
    if(e >= N_EDGESC) return;
    int d = ei[N_EDGESC + e];
    int p = atomicAdd(&cursor[d], 1);
    csr_src[p] = ei[e];
    csr_ea[p]  = ea[2*e]*3 + ea[2*e+1];
}

// ---------------- gather-sum aggregation -> bf16 agg[i][K1] -----------------
// BN=0: src = h (stride LD4 float4), plain gather (layer 0).
// BN=1: src = dout (stride 75 float4); per element apply relu(a*x+b) where
//       a,b are the BN affine params of the PREVIOUS layer.
template<int BN>
__global__ void k_aggT(const float* __restrict__ src, const float* __restrict__ etab_l,
                       const float* __restrict__ aff,
                       const int* __restrict__ offs, const int* __restrict__ csr_src,
                       const int* __restrict__ csr_ea, unsigned short* __restrict__ agg){
    int idx = blockIdx.x*blockDim.x + threadIdx.x;
    if(idx >= N_NODESC*80) return;
    int i = idx / 80, c = idx % 80;
    ushort4 out;
    if(c < 75){
        const float4* s4 = (const float4*)src;
        const float4* et = (const float4*)etab_l;
        const int stride = BN ? 75 : LD4;
        float4 a4, b4;
        if(BN){ a4 = ((const float4*)aff)[c]; b4 = ((const float4*)aff)[75 + c]; }
        #define LOADV(s_, v_) { float4 x_ = s4[(size_t)(s_)*stride + c];          \
            if(BN){ v_.x = fmaxf(fmaf(x_.x,a4.x,b4.x),0.f);                       \
                    v_.y = fmaxf(fmaf(x_.y,a4.y,b4.y),0.f);                       \
                    v_.z = fmaxf(fmaf(x_.z,a4.z,b4.z),0.f);                       \
                    v_.w = fmaxf(fmaf(x_.w,a4.w,b4.w),0.f); } else v_ = x_; }
        float4 v;
        LOADV(i, v)
        float4 acc = f4add(v, et[12*LD4 + c]);   // self loop, attr idx 12
        int j0 = offs[i], j1 = offs[i+1];
        for(int j=j0; j<j1; j++){
            int s = csr_src[j];
            int t = csr_ea[j];
            LOADV(s, v)
            acc = f4add(acc, f4add(v, et[t*LD4 + c]));
        }
        #undef LOADV
        out.x = f2bf(acc.x); out.y = f2bf(acc.y);
        out.z = f2bf(acc.z); out.w = f2bf(acc.w);
    } else {
        out.x = out.y = out.z = out.w = 0;
    }
    *(ushort4*)(agg + (size_t)i*K1 + c*4) = out;
}

// ---------------- BN affine precompute: a = g*rsqrt(var+eps), b = bt - m*a --
__global__ void k_bnaff(const float* __restrict__ stats, const float* __restrict__ g,
                        const float* __restrict__ bt, float* __restrict__ aff){
    int c = blockIdx.x*blockDim.x + threadIdx.x;
    if(c >= EMB) return;
    const float inv_n = 1.0f/(float)N_NODESC;
    float m = stats[c]*inv_n;
    float var = stats[EMB + c]*inv_n - m*m;
    float a = g[c]*rsqrtf(var + BN_EPS);
    aff[c] = a;
    aff[EMB + c] = bt[c] - m*a;
}

// ---------------- bf16 MFMA GEMM: C = epi(A @ Bt^T + bias) ------------------
// 128x128 block tile, 512 threads, 8 waves = 4 positions (2x2, 64x64 wave
// tile) x 2-way K-SPLIT: wave (ks=wv>>2) computes only steps with
// (kc&1)==ks.  Per active step: 8 ds_read_b128 per 16 MFMA = 0.5 KB/MFMA
// (vs R8's 0.75) — LDS-read BW was the largest per-CU consumer (≈57 µs of
// R8's 103 µs GEMM2).  Sync structure is BYTE-IDENTICAL to proven R8:
// 3-buf counted vmcnt(2), fenced prologue, unconditional waits/barriers
// (compute predicate is wave-uniform; staging unconditional).
// After K-loop: wave pairs (p, p+4) combine partial acc via LDS (stride-68
// pad -> 2-way conflicts only), then epilogues run on waves ks==0.
// EPI 0: bf16 LDS-bounce ([128][136]) store, +bias, relu.
// EPI 1: fused BN stats, fp32 LDS-bounce (two 64-row halves), col<300.
template<int EPI, int KS, int NX>
__global__ __launch_bounds__(512, 4) void k_mgemm(
    const unsigned short* __restrict__ A,
    const unsigned short* __restrict__ Bt,
    const float* __restrict__ bias,
    void* __restrict__ Cptr, int M, int ldc,
    float* __restrict__ stats, int nwg)
{
    __shared__ char smem_c[3*16384 + 4096];    // 3 bufs (A 8K | B 8K) + red 4K
    unsigned short* smem_u = (unsigned short*)smem_c;

    // ---- XCD bijective remap, x-major decomposition ------------------------
    int bid = blockIdx.x;
    int q = nwg >> 3, r = nwg & 7;
    int xcd = bid & 7, lo = bid >> 3;
    int wg = (xcd < r) ? (xcd*(q+1) + lo) : (r*(q+1) + (xcd - r)*q + lo);
    int bx = wg % NX, by = wg / NX;
    int m0 = by*128, n0 = bx*128;

    const int tid = threadIdx.x;
    const int wv = tid >> 6, ln = tid & 63;
    const int ks = wv >> 2;                    // K-split half (0/1)
    const int p  = wv & 3;                     // output position
    const int wvm = p >> 1, wvn = p & 1;       // rows wvm*64, cols wvn*64
    const int lr = ln & 15, hi = ln >> 4;

    // ---- staging: 1 A-chunk + 1 B-chunk per thread per tile ----------------
    const int rS = tid >> 2, cS = tid & 3;     // row 0..127, phys chunk 0..3
    int gA = m0 + rS; if(gA >= M) gA = M-1;
    const unsigned short* srcA = A  + (size_t)gA*(KS*32)        + ((cS ^ ((rS>>1)&3))<<3);
    const unsigned short* srcB = Bt + (size_t)(n0 + rS)*(KS*32) + ((cS ^ ((rS>>1)&3))<<3);

    f32x4 acc[4][4] = {};

    // stage tile t into buf t%3 (2 loads/thread -> vmcnt counts 2 per tile)
    #define STAGE(t) { \
        char* db_ = smem_c + ((t)%3)*16384; \
        GLOAD16(srcA + (t)*32, db_ + tid*16); \
        GLOAD16(srcB + (t)*32, db_ + 8192 + tid*16); }

    // ---- prologue: tiles 0,1 — fenced so issue order matches vmcnt ---------
    STAGE(0)
    __builtin_amdgcn_sched_barrier(0);
    STAGE(1)
    __builtin_amdgcn_sched_barrier(0);

    // per-lane ds_read offsets (ushort units), row-constant across kc
    int offA[4], offB[4];
    #pragma unroll
    for(int m=0;m<4;m++){
        int row = wvm*64 + m*16 + lr;          // 0..127
        offA[m] = row*32 + ((hi ^ ((row>>1)&3))<<3);
    }
    #pragma unroll
    for(int n=0;n<4;n++){
        int brow = wvn*64 + n*16 + lr;         // 0..127
        offB[n] = 4096 + brow*32 + ((hi ^ ((brow>>1)&3))<<3);
    }

    #pragma unroll
    for(int kc=0; kc<KS; kc++){
        // wait for tile kc (allow tile kc+1's 2 loads to stay in flight)
        if(kc == KS-1) asm volatile("s_waitcnt vmcnt(0) lgkmcnt(0)" ::: "memory");
        else           asm volatile("s_waitcnt vmcnt(2) lgkmcnt(0)" ::: "memory");
        __builtin_amdgcn_s_barrier();
        __builtin_amdgcn_sched_barrier(0);   // keep STAGE strictly after barrier
        if(kc+2 < KS) STAGE(kc+2)
        if((kc & 1) == ks){                  // wave-uniform K-split predicate
            const unsigned short* bufu = smem_u + (kc%3)*8192;
            short8 av[4], bv[4];
            #pragma unroll
            for(int m=0;m<4;m++) av[m] = *(const short8*)(bufu + offA[m]);
            #pragma unroll
            for(int n=0;n<4;n++) bv[n] = *(const short8*)(bufu + offB[n]);
            __builtin_amdgcn_s_setprio(1);
            #pragma unroll
            for(int m=0;m<4;m++)
                #pragma unroll
                for(int n=0;n<4;n++)
                    acc[m][n] = __builtin_amdgcn_mfma_f32_16x16x32_bf16(
                                    av[m], bv[n], acc[m][n], 0, 0, 0);
            __builtin_amdgcn_s_setprio(0);
        }
    }
    #undef STAGE

    __syncthreads();   // full drain; LDS free for combine/epilogue reuse

    // ---- K-split pair combine: round r2 handles positions {2r2, 2r2+1} -----
    // ks==1 wave writes its partial acc; ks==0 partner adds. Stride 68 floats
    // (row step 272B -> hi groups hit 2 bank sets, 2-way = free).
    {
        float* cmb = (float*)smem_c;           // 2 x 64x68 f = 34,816 B
        #pragma unroll
        for(int r2=0; r2<2; r2++){
            if(ks == 1 && wvm == r2){
                int base = wvn*4352;
                #pragma unroll
                for(int m=0;m<4;m++)
                    #pragma unroll
                    for(int n=0;n<4;n++)
                        #pragma unroll
                        for(int j=0;j<4;j++)
                            cmb[base + (m*16 + hi*4 + j)*68 + n*16 + lr] = acc[m][n][j];
            }
            __syncthreads();
            if(ks == 0 && wvm == r2){
                int base = wvn*4352;
                #pragma unroll
                for(int m=0;m<4;m++)
                    #pragma unroll
                    for(int n=0;n<4;n++)
                        #pragma unroll
                        for(int j=0;j<4;j++)
                            acc[m][n][j] += cmb[base + (m*16 + hi*4 + j)*68 + n*16 + lr];
            }
            __syncthreads();
        }
    }

    // epilogues: waves ks==0 hold the full 64x64 quadrant accumulators
    if(EPI == 0){
        // ---- bounce C tile (bf16) through LDS [128][136], short8 stores ----
        unsigned short* Cs = smem_u;          // 128*136*2 = 34,816 B
        unsigned short* Cb = (unsigned short*)Cptr;
        if(ks == 0){
            #pragma unroll
            for(int n=0;n<4;n++){
                int col = wvn*64 + n*16 + lr;
                float bsv = bias[n0 + col];
                #pragma unroll
                for(int m=0;m<4;m++){
                    #pragma unroll
                    for(int j=0;j<4;j++){
                        int row = wvm*64 + m*16 + hi*4 + j;
                        Cs[row*136 + col] = f2bf(fmaxf(acc[m][n][j] + bsv, 0.f));
                    }
                }
            }
        }
        __syncthreads();
        #pragma unroll
        for(int i=0;i<4;i++){
            int id = i*512 + tid;
            int rr = id >> 4, ch = id & 15;    // 128 rows x 16 chunks
            int gr = m0 + rr;
            if(gr < M)
                *(short8*)(Cb + (size_t)gr*ldc + n0 + ch*8) =
                    *(const short8*)(Cs + rr*136 + ch*8);
        }
    } else {
        // ---- fused BN stats (cross-wvm via red), fp32 half bounce ----------
        float* Cf = (float*)Cptr;
        float* red = (float*)(smem_c + 3*16384);   // 1024 floats
        if(ks == 0){
            #pragma unroll
            for(int n=0;n<4;n++){
                int col = n0 + wvn*64 + n*16 + lr;
                bool cok = (col < EMB);
                float bsv = cok ? bias[col] : 0.f;
                float sS = 0.f, sQ = 0.f;
                #pragma unroll
                for(int m=0;m<4;m++){
                    #pragma unroll
                    for(int j=0;j<4;j++){
                        int row = m0 + wvm*64 + m*16 + hi*4 + j;
                        if(cok && row < M){
                            float v = acc[m][n][j] + bsv;
                            sS += v; sQ += v*v;
                        }
                    }
                }
                sS += __shfl_xor(sS, 16); sQ += __shfl_xor(sQ, 16);
                sS += __shfl_xor(sS, 32); sQ += __shfl_xor(sQ, 32);
                if(hi == 0){
                    red[(wv*4+n)*16 + lr]       = sS;
                    red[512 + (wv*4+n)*16 + lr] = sQ;
                }
            }
        }
        __syncthreads();
        if(tid < 128){
            int twvn = tid >> 6, tn = (tid >> 4) & 3, tlr = tid & 15;
            float S = 0.f, Q = 0.f;
            #pragma unroll
            for(int wm2=0; wm2<2; wm2++){
                int w = wm2*2 + twvn;          // wave index = wvm*2+wvn
                S += red[(w*4+tn)*16 + tlr];
                Q += red[512 + (w*4+tn)*16 + tlr];
            }
            int c2 = n0 + twvn*64 + tn*16 + tlr;
            if(c2 < EMB){
                atomicAdd(&stats[c2], S);
                atomicAdd(&stats[EMB + c2], Q);
            }
        }
        __syncthreads();
        // fp32 bounce: half h covers tile rows [h*64, h*64+64)
        float* Cs = (float*)smem_c;                // [64][132] = 33,792 B
        #pragma unroll
        for(int half=0; half<2; half++){
            if(ks == 0 && wvm == half){
                #pragma unroll
                for(int n=0;n<4;n++){
                    int col = wvn*64 + n*16 + lr;
                    float bsv = (n0 + col < EMB) ? bias[n0 + col] : 0.f;
                    #pragma unroll
                    for(int m=0;m<4;m++){
                        #pragma unroll
                        for(int j=0;j<4;j++){
                            int rl = m*16 + hi*4 + j;      // 0..63
                            Cs[rl*132 + col] = acc[m][n][j] + bsv;
                        }
                    }
                }
            }
            __syncthreads();
            #pragma unroll
            for(int i=0;i<4;i++){
                int id = i*512 + tid;
                int rr = id >> 5, c4 = id & 31;    // 64 rows x 32 float4
                int col = n0 + c4*4;
                int gr = m0 + half*64 + rr;
                if(col < EMB && gr < M)
                    *(float4*)(Cf + (size_t)gr*ldc + col) =
                        *(const float4*)(Cs + rr*132 + c4*4);
            }
            __syncthreads();
        }
    }
}

// ---------------- BN apply (final layer only: no relu, writes dout) ---------
__global__ void k_bnapply(const float* __restrict__ X, const float* __restrict__ stats,
                          const float* __restrict__ g, const float* __restrict__ bt,
                          float* __restrict__ dout){
    int idx = blockIdx.x*blockDim.x + threadIdx.x;
    if(idx >= N_NODESC*75) return;
    int i = idx / 75, c = idx % 75;
    const float4* X4 = (const float4*)X;
    float4 v  = X4[(size_t)i*75 + c];
    float4 s  = ((const float4*)stats)[c];
    float4 q  = ((const float4*)stats)[75 + c];
    float4 gg = ((const float4*)g)[c];
    float4 bb = ((const float4*)bt)[c];
    const float inv_n = 1.0f/(float)N_NODESC;
    #define BN1(f) { float m = s.f*inv_n; float var = q.f*inv_n - m*m;          \
                     float r = rsqrtf(var + BN_EPS);                             \
                     v.f = (v.f - m)*r*gg.f + bb.f; }
    BN1(x) BN1(y) BN1(z) BN1(w)
    #undef BN1
    ((float4*)dout)[(size_t)i*75 + c] = v;
}

// ----------------------------------------------------------------------------
extern "C" void kernel_launch(void* const* d_in, const int* in_sizes, int n_in,
                              void* d_out, int out_size, void* d_ws, size_t ws_size,
                              hipStream_t stream) {
    const int*   x     = (const int*)d_in[0];
    const int*   ei    = (const int*)d_in[1];
    const int*   ea    = (const int*)d_in[2];
    const float* aemb1 = (const float*)d_in[3];
    const float* aemb2 = (const float*)d_in[4];
    const float* eemb1 = (const float*)d_in[5];
    const float* eemb2 = (const float*)d_in[6];
    const float* W1    = (const float*)d_in[7];
    const float* b1    = (const float*)d_in[8];
    const float* W2    = (const float*)d_in[9];
    const float* b2    = (const float*)d_in[10];
    const float* gamma = (const float*)d_in[11];
    const float* beta  = (const float*)d_in[12];
    float* dout = (float*)d_out;

    // workspace layout
    float* h      = (float*)d_ws;                              // 100000*304 f
    float* bias1p = h + (size_t)N_NODESC*LD;                   // 5*640 f
    float* etab   = bias1p + LAYERS*N1;                        // 5*18*304 f
    float* stats  = etab + LAYERS*18*LD;                       // 640 f
    float* aff    = stats + 640;                               // 640 f
    unsigned short* agg  = (unsigned short*)(aff + 640);       // 100000*320 bf16
    unsigned short* hmid = agg  + (size_t)N_NODESC*K1;         // 100000*640 bf16
    unsigned short* wb1t = hmid + (size_t)N_NODESC*N1;         // 5*640*320 bf16
    unsigned short* wb2t = wb1t + (size_t)LAYERS*N1*K1;        // 5*384*640 bf16
    int*   deg     = (int*)(wb2t + (size_t)LAYERS*N2*K2);
    int*   offs    = deg    + N_NODESC;
    int*   cursor  = offs   + N_NODESC + 1;
    int*   csr_src = cursor + N_NODESC + 1;
    int*   csr_ea  = csr_src + N_EDGESC;
    int*   bsum    = csr_ea + N_EDGESC;
    int*   bpre    = bsum + NB_SCAN;

    const int nb_nf4 = (N_NODESC*LD4 + 255)/256;

    // one-time setup
    k_atom<<<nb_nf4, 256, 0, stream>>>(x, aemb1, aemb2, h);
    k_etab<<<(LAYERS*18*LD4 + 255)/256, 256, 0, stream>>>(eemb1, eemb2, etab);
    k_prepw1<<<(LAYERS*N1*K1 + 255)/256, 256, 0, stream>>>(W1, wb1t);
    k_prepw2<<<(LAYERS*N2*K2 + 255)/256, 256, 0, stream>>>(W2, wb2t);
    k_prepb1<<<(LAYERS*N1 + 255)/256, 256, 0, stream>>>(b1, bias1p);
    k_zero_i<<<(N_NODESC + 255)/256, 256, 0, stream>>>(deg, N_NODESC);
    k_deg<<<(N_EDGESC + 255)/256, 256, 0, stream>>>(ei, deg);
    k_bsum<<<NB_SCAN, 256, 0, stream>>>(deg, bsum);
    k_bscan<<<1, 512, 0, stream>>>(bsum, bpre, offs);
    k_offs<<<NB_SCAN, 256, 0, stream>>>(deg, bpre, offs, cursor);
    k_fill<<<(N_EDGESC + 255)/256, 256, 0, stream>>>(ei, ea, cursor, csr_src, csr_ea);

    const int MT = (N_NODESC + 127)/128;   // 782 M-tiles of 128 rows
    const int nwg1 = 5*MT, nwg2 = 3*MT;
    const int nb_agg = (N_NODESC*80 + 255)/256;
    for(int l=0; l<LAYERS; l++){
        if(l == 0)
            k_aggT<0><<<nb_agg, 256, 0, stream>>>(
                h, etab, stats /*unused*/, offs, csr_src, csr_ea, agg);
        else
            k_aggT<1><<<nb_agg, 256, 0, stream>>>(
                dout, etab + (size_t)l*18*LD, aff, offs, csr_src, csr_ea, agg);
        k_zero_f<<<(2*EMB + 255)/256, 256, 0, stream>>>(stats, 2*EMB);
        k_mgemm<0, 10, 5><<<nwg1, 512, 0, stream>>>(
            agg, wb1t + (size_t)l*N1*K1, bias1p + (size_t)l*N1,
            hmid, N_NODESC, N1, nullptr, nwg1);
        k_mgemm<1, 20, 3><<<nwg2, 512, 0, stream>>>(
            hmid, wb2t + (size_t)l*N2*K2, b2 + (size_t)l*EMB,
            dout, N_NODESC, EMB, stats, nwg2);
        if(l < LAYERS-1)
            k_bnaff<<<2, 256, 0, stream>>>(stats, gamma + (size_t)l*EMB,
                                           beta + (size_t)l*EMB, aff);
        else
            k_bnapply<<<(N_NODESC*75 + 255)/256, 256, 0, stream>>>(
                dout, stats, gamma + (size_t)l*EMB, beta + (size_t)l*EMB, dout);
    }
}

// Round 11
// 1427.186 us; speedup vs baseline: 1.0352x; 1.0352x over previous
//
#include <hip/hip_runtime.h>
#include <hip/hip_bf16.h>

#define N_NODESC 100000
#define N_EDGESC 250000
#define EMB 300
#define LD 304      // fp32 h / etab stride (float4-friendly)
#define LD4 76
#define LAYERS 5
#define BN_EPS 1e-5f

#define K1 320      // padded K for GEMM1 (agg stride)
#define N1 640      // padded N for GEMM1 (hmid stride, = K for GEMM2)
#define K2 640
#define N2 384      // padded N for GEMM2 (output guarded to 300)
#define HB 320      // houtb stride (bf16 intermediate hout)

#define NB_SCAN 391 // ceil(100000/256)

typedef __attribute__((ext_vector_type(8))) short short8;
typedef __attribute__((ext_vector_type(8))) unsigned short ushort8v;
typedef __attribute__((ext_vector_type(4))) float f32x4;

#define GLOAD16(g, l) __builtin_amdgcn_global_load_lds( \
    (const __attribute__((address_space(1))) void*)(g), \
    (__attribute__((address_space(3))) void*)(l), 16, 0, 0)

__device__ __forceinline__ float4 f4add(float4 a, float4 b){
    return make_float4(a.x+b.x, a.y+b.y, a.z+b.z, a.w+b.w);
}
__device__ __forceinline__ unsigned short f2bf(float f){
    __hip_bfloat16 h = __float2bfloat16(f);
    return *(unsigned short*)&h;
}
__device__ __forceinline__ float bf2f(unsigned short u){
    unsigned int x = ((unsigned int)u) << 16;
    union { unsigned int i; float f; } c; c.i = x; return c.f;
}

// ---------------- utility zero kernels --------------------------------------
__global__ void k_zero_i(int* p, int n){
    int i = blockIdx.x*blockDim.x + threadIdx.x;
    if(i < n) p[i] = 0;
}
__global__ void k_zero_f(float* p, int n){
    int i = blockIdx.x*blockDim.x + threadIdx.x;
    if(i < n) p[i] = 0.f;
}

// ---------------- atom encoder: h = emb1[x0] + emb2[x1], fp32 stride LD -----
__global__ void k_atom(const int* __restrict__ x,
                       const float* __restrict__ e1,
                       const float* __restrict__ e2,
                       float* __restrict__ h){
    int idx = blockIdx.x*blockDim.x + threadIdx.x;
    if(idx >= N_NODESC*LD4) return;
    int i = idx / LD4, c = idx % LD4;
    float4 v = make_float4(0,0,0,0);
    if(c < 75){
        int i0 = x[2*i], i1 = x[2*i+1];
        const float4* r1 = (const float4*)(e1 + (size_t)i0*EMB);
        const float4* r2 = (const float4*)(e2 + (size_t)i1*EMB);
        v = f4add(r1[c], r2[c]);
    }
    ((float4*)h)[idx] = v;
}

// ---------------- combined edge-embedding table etab[l][ea0*3+ea1][LD] ------
__global__ void k_etab(const float* __restrict__ e1,
                       const float* __restrict__ e2,
                       float* __restrict__ etab){
    int idx = blockIdx.x*blockDim.x + threadIdx.x;
    if(idx >= LAYERS*18*LD4) return;
    int l = idx / (18*LD4);
    int r = idx % (18*LD4);
    int c = r / LD4, f = r % LD4;
    float4 v = make_float4(0,0,0,0);
    if(f < 75){
        const float4* r1 = (const float4*)(e1 + (size_t)(l*6 + c/3)*EMB);
        const float4* r2 = (const float4*)(e2 + (size_t)(l*3 + c%3)*EMB);
        v = f4add(r1[f], r2[f]);
    }
    ((float4*)etab)[idx] = v;
}

// ---------------- weight prep: B^T padded bf16 ------------------------------
__global__ void k_prepw1(const float* __restrict__ W1, unsigned short* __restrict__ wb){
    int idx = blockIdx.x*blockDim.x + threadIdx.x;
    if(idx >= LAYERS*N1*K1) return;
    int l = idx / (N1*K1);
    int r = idx % (N1*K1);
    int n = r / K1, k = r % K1;
    float v = (n < 600 && k < EMB) ? W1[((size_t)l*EMB + k)*600 + n] : 0.f;
    wb[idx] = f2bf(v);
}
__global__ void k_prepw2(const float* __restrict__ W2, unsigned short* __restrict__ wb){
    int idx = blockIdx.x*blockDim.x + threadIdx.x;
    if(idx >= LAYERS*N2*K2) return;
    int l = idx / (N2*K2);
    int r = idx % (N2*K2);
    int n = r / K2, k = r % K2;
    float v = (n < EMB && k < 600) ? W2[((size_t)l*600 + k)*EMB + n] : 0.f;
    wb[idx] = f2bf(v);
}
__global__ void k_prepb1(const float* __restrict__ b1, float* __restrict__ bp){
    int idx = blockIdx.x*blockDim.x + threadIdx.x;
    if(idx >= LAYERS*N1) return;
    int l = idx / N1, n = idx % N1;
    bp[idx] = (n < 600) ? b1[(size_t)l*600 + n] : 0.f;
}

// ---------------- CSR build -------------------------------------------------
__global__ void k_deg(const int* __restrict__ ei, int* __restrict__ deg){
    int e = blockIdx.x*blockDim.x + threadIdx.x;
    if(e >= N_EDGESC) return;
    atomicAdd(&deg[ei[N_EDGESC + e]], 1);
}

__global__ void k_bsum(const int* __restrict__ deg, int* __restrict__ bsum){
    int g = blockIdx.x*256 + threadIdx.x;
    int v = (g < N_NODESC) ? deg[g] : 0;
    #pragma unroll
    for(int o=32;o>0;o>>=1) v += __shfl_down(v, o);
    __shared__ int sw[4];
    if((threadIdx.x & 63) == 0) sw[threadIdx.x>>6] = v;
    __syncthreads();
    if(threadIdx.x == 0) bsum[blockIdx.x] = sw[0]+sw[1]+sw[2]+sw[3];
}

__global__ void k_bscan(const int* __restrict__ bsum, int* __restrict__ bpre,
                        int* __restrict__ offs){
    __shared__ int sh[512];
    int t = threadIdx.x;
    int v = (t < NB_SCAN) ? bsum[t] : 0;
    sh[t] = v; __syncthreads();
    for(int o=1;o<512;o<<=1){
        int u = (t >= o) ? sh[t-o] : 0;
        __syncthreads();
        sh[t] += u;
        __syncthreads();
    }
    if(t < NB_SCAN) bpre[t] = sh[t] - v;
    if(t == NB_SCAN-1) offs[N_NODESC] = sh[t];
}

__global__ void k_offs(const int* __restrict__ deg, const int* __restrict__ bpre,
                       int* __restrict__ offs, int* __restrict__ cursor){
    __shared__ int sh[256];
    int t = threadIdx.x;
    int g = blockIdx.x*256 + t;
    int v = (g < N_NODESC) ? deg[g] : 0;
    sh[t] = v; __syncthreads();
    for(int o=1;o<256;o<<=1){
        int u = (t >= o) ? sh[t-o] : 0;
        __syncthreads();
        sh[t] += u;
        __syncthreads();
    }
    if(g < N_NODESC){
        int e = bpre[blockIdx.x] + sh[t] - v;
        offs[g] = e; cursor[g] = e;
    }
}

__global__ void k_fill(const int* __restrict__ ei, const int* __restrict__ ea,
                       int* __restrict__ cursor,
                       int* __restrict__ csr_src, int* __restrict__ csr_ea){
    int e = blockIdx.x*blockDim.x + threadIdx.x;
    if(e >= N_EDGESC) return;
    int d = ei[N_EDGESC + e];
    int p = atomicAdd(&cursor[d], 1);
    csr_src[p] = ei[e];
    csr_ea[p]  = ea[2*e]*3 + ea[2*e+1];
}

// ---------------- layer-0 gather (fp32 h source) ----------------------------
__global__ void k_agg0(const float* __restrict__ h, const float* __restrict__ etab_l,
                       const int* __restrict__ offs, const int* __restrict__ csr_src,
                       const int* __restrict__ csr_ea, unsigned short* __restrict__ agg){
    int idx = blockIdx.x*blockDim.x + threadIdx.x;
    if(idx >= N_NODESC*80) return;
    int i = idx / 80, c = idx % 80;
    ushort4 out;
    if(c < 75){
        const float4* h4 = (const float4*)h;
        const float4* et = (const float4*)etab_l;
        float4 acc = f4add(h4[(size_t)i*LD4 + c], et[12*LD4 + c]);
        int j0 = offs[i], j1 = offs[i+1];
        for(int j=j0; j<j1; j++){
            int s = csr_src[j];
            int t = csr_ea[j];
            acc = f4add(acc, f4add(h4[(size_t)s*LD4 + c], et[t*LD4 + c]));
        }
        out.x = f2bf(acc.x); out.y = f2bf(acc.y);
        out.z = f2bf(acc.z); out.w = f2bf(acc.w);
    } else {
        out.x = out.y = out.z = out.w = 0;
    }
    *(ushort4*)(agg + (size_t)i*K1 + c*4) = out;
}

// ---------------- layers 1-4 gather (bf16 houtb source + BN affine) ---------
// 8 cols/thread: loads ushort8 (16B), applies relu(a*x+b) in fp32 per elem,
// accumulates fp32, writes bf16 agg chunk. Cols >= 300 forced zero (a=b=0,
// etab pad cols are zero).
__global__ void k_aggB(const unsigned short* __restrict__ src,
                       const float* __restrict__ etab_l,
                       const float* __restrict__ aff,
                       const int* __restrict__ offs, const int* __restrict__ csr_src,
                       const int* __restrict__ csr_ea, unsigned short* __restrict__ agg){
    int idx = blockIdx.x*blockDim.x + threadIdx.x;
    if(idx >= N_NODESC*40) return;
    int i = idx / 40, c = idx % 40;
    ushort8v out = (ushort8v){0,0,0,0,0,0,0,0};
    if(c < 38){
        const int c8 = c*8;
        float a[8], b[8], accv[8];
        #pragma unroll
        for(int e=0;e<8;e++){
            int col = c8 + e;
            bool ok = col < EMB;
            a[e] = ok ? aff[col]       : 0.f;
            b[e] = ok ? aff[EMB + col] : 0.f;
        }
        ushort8v sv = *(const ushort8v*)(src + (size_t)i*HB + c8);
        const float* e12 = etab_l + 12*LD + c8;
        #pragma unroll
        for(int e=0;e<8;e++)
            accv[e] = fmaxf(fmaf(bf2f(sv[e]), a[e], b[e]), 0.f) + e12[e];
        int j0 = offs[i], j1 = offs[i+1];
        for(int j=j0; j<j1; j++){
            int s = csr_src[j];
            int t = csr_ea[j];
            ushort8v nv = *(const ushort8v*)(src + (size_t)s*HB + c8);
            const float* et = etab_l + t*LD + c8;
            #pragma unroll
            for(int e=0;e<8;e++)
                accv[e] += fmaxf(fmaf(bf2f(nv[e]), a[e], b[e]), 0.f) + et[e];
        }
        #pragma unroll
        for(int e=0;e<8;e++) out[e] = f2bf(accv[e]);
    }
    *(ushort8v*)(agg + (size_t)i*K1 + c*8) = out;
}

// ---------------- BN affine precompute: a = g*rsqrt(var+eps), b = bt - m*a --
__global__ void k_bnaff(const float* __restrict__ stats, const float* __restrict__ g,
                        const float* __restrict__ bt, float* __restrict__ aff){
    int c = blockIdx.x*blockDim.x + threadIdx.x;
    if(c >= EMB) return;
    const float inv_n = 1.0f/(float)N_NODESC;
    float m = stats[c]*inv_n;
    float var = stats[EMB + c]*inv_n - m*m;
    float a = g[c]*rsqrtf(var + BN_EPS);
    aff[c] = a;
    aff[EMB + c] = bt[c] - m*a;
}

// ---------------- bf16 MFMA GEMM: C = epi(A @ Bt^T + bias) ------------------
// EXACT R8 shell (proven best: 1348 µs total, 52% occ): 128x128 tile, 512
// threads, 8 waves (2M x 4N, wave tile 64x32), BK=32, 3-buffer LDS +
// counted-vmcnt pipeline; per step {vmcnt(2) lgkmcnt(0); s_barrier; SB(0);
// STAGE(kc+2); ds_read; setprio(1); 8 MFMA; setprio(0)}. vmcnt(0) only last.
// Prologue STAGEs fenced (R6 lesson). Chunk-swizzle ^((row>>1)&3) both sides.
// EPI 0: bf16 LDS-bounce [128][144] store, +bias, relu (hmid, ldc=N1).
// EPI 1: fp32 stats + fp32 LDS-bounce halves [64][132] (final dout, ldc=EMB).
// EPI 2: fp32 stats + bf16 LDS-bounce [128][136], col<300 mask (houtb, ldc=HB).
template<int EPI, int KS, int NX>
__global__ __launch_bounds__(512) void k_mgemm(
    const unsigned short* __restrict__ A,
    const unsigned short* __restrict__ Bt,
    const float* __restrict__ bias,
    void* __restrict__ Cptr, int M, int ldc,
    float* __restrict__ stats, int nwg)
{
    __shared__ char smem_c[3*16384 + 1024];    // 3 bufs (A 8K | B 8K) + red
    unsigned short* smem_u = (unsigned short*)smem_c;

    // ---- XCD bijective remap, x-major decomposition ------------------------
    int bid = blockIdx.x;
    int q = nwg >> 3, r = nwg & 7;
    int xcd = bid & 7, lo = bid >> 3;
    int wg = (xcd < r) ? (xcd*(q+1) + lo) : (r*(q+1) + (xcd - r)*q + lo);
    int bx = wg % NX, by = wg / NX;
    int m0 = by*128, n0 = bx*128;

    const int tid = threadIdx.x;
    const int wv = tid >> 6, ln = tid & 63;
    const int wvm = wv >> 2, wvn = wv & 3;     // wave tile: rows wvm*64, cols wvn*32
    const int lr = ln & 15, hi = ln >> 4;

    // ---- staging: 1 chunk of A + 1 of B per thread per tile ----------------
    const int rS = tid >> 2, cS = tid & 3;     // row 0..127, phys chunk 0..3
    int gA = m0 + rS; if(gA >= M) gA = M-1;
    const unsigned short* srcA = A  + (size_t)gA*(KS*32)        + ((cS ^ ((rS>>1)&3))<<3);
    const unsigned short* srcB = Bt + (size_t)(n0 + rS)*(KS*32) + ((cS ^ ((rS>>1)&3))<<3);

    f32x4 acc[4][2] = {};

    // stage tile t into buf t%3 (2 loads/thread -> vmcnt counts 2 per tile)
    #define STAGE(t) { \
        char* db_ = smem_c + ((t)%3)*16384; \
        GLOAD16(srcA + (t)*32, db_ + tid*16); \
        GLOAD16(srcB + (t)*32, db_ + 8192 + tid*16); }

    // ---- prologue: tiles 0,1 — fenced so issue order matches vmcnt ---------
    STAGE(0)
    __builtin_amdgcn_sched_barrier(0);
    STAGE(1)
    __builtin_amdgcn_sched_barrier(0);

    // per-lane ds_read offsets (ushort units), row-constant across kc
    int offA[4], offB[2];
    #pragma unroll
    for(int m=0;m<4;m++){
        int row = wvm*64 + m*16 + lr;
        offA[m] = row*32 + ((hi ^ ((row>>1)&3))<<3);
    }
    #pragma unroll
    for(int n=0;n<2;n++){
        int brow = wvn*32 + n*16 + lr;
        offB[n] = 4096 + brow*32 + ((hi ^ ((brow>>1)&3))<<3);
    }

    #pragma unroll
    for(int kc=0; kc<KS; kc++){
        // wait for tile kc (allow tile kc+1's 2 loads to stay in flight)
        if(kc == KS-1) asm volatile("s_waitcnt vmcnt(0) lgkmcnt(0)" ::: "memory");
        else           asm volatile("s_waitcnt vmcnt(2) lgkmcnt(0)" ::: "memory");
        __builtin_amdgcn_s_barrier();
        __builtin_amdgcn_sched_barrier(0);   // keep STAGE strictly after barrier
        if(kc+2 < KS) STAGE(kc+2)
        const unsigned short* bufu = smem_u + (kc%3)*8192;
        short8 av[4], bv[2];
        #pragma unroll
        for(int m=0;m<4;m++) av[m] = *(const short8*)(bufu + offA[m]);
        #pragma unroll
        for(int n=0;n<2;n++) bv[n] = *(const short8*)(bufu + offB[n]);
        __builtin_amdgcn_s_setprio(1);
        #pragma unroll
        for(int m=0;m<4;m++)
            #pragma unroll
            for(int n=0;n<2;n++)
                acc[m][n] = __builtin_amdgcn_mfma_f32_16x16x32_bf16(
                                av[m], bv[n], acc[m][n], 0, 0, 0);
        __builtin_amdgcn_s_setprio(0);
    }
    #undef STAGE

    __syncthreads();   // full drain; LDS free for epilogue reuse

    if(EPI == 0){
        // ---- bounce C tile (bf16) through LDS (stride 144), short8 stores --
        unsigned short* Cs = smem_u;          // [128][144] = 36,864 B
        unsigned short* Cb = (unsigned short*)Cptr;
        #pragma unroll
        for(int n=0;n<2;n++){
            int col = wvn*32 + n*16 + lr;
            float bsv = bias[n0 + col];
            #pragma unroll
            for(int m=0;m<4;m++){
                #pragma unroll
                for(int j=0;j<4;j++){
                    int row = wvm*64 + m*16 + hi*4 + j;
                    Cs[row*144 + col] = f2bf(fmaxf(acc[m][n][j] + bsv, 0.f));
                }
            }
        }
        __syncthreads();
        #pragma unroll
        for(int i=0;i<4;i++){
            int id = i*512 + tid;
            int rr = id >> 4, ch = id & 15;
            int gr = m0 + rr;
            if(gr < M)
                *(short8*)(Cb + (size_t)gr*ldc + n0 + ch*8) =
                    *(const short8*)(Cs + rr*144 + ch*8);
        }
    } else {
        // ---- fused BN stats (identical for EPI 1/2): from fp32 acc ---------
        float* red = (float*)(smem_c + 3*16384);   // 256 floats
        #pragma unroll
        for(int n=0;n<2;n++){
            int col = n0 + wvn*32 + n*16 + lr;
            bool cok = (col < EMB);
            float bsv = cok ? bias[col] : 0.f;
            float sS = 0.f, sQ = 0.f;
            #pragma unroll
            for(int m=0;m<4;m++){
                #pragma unroll
                for(int j=0;j<4;j++){
                    int row = m0 + wvm*64 + m*16 + hi*4 + j;
                    if(cok && row < M){
                        float v = acc[m][n][j] + bsv;
                        sS += v; sQ += v*v;
                    }
                }
            }
            sS += __shfl_xor(sS, 16); sQ += __shfl_xor(sQ, 16);
            sS += __shfl_xor(sS, 32); sQ += __shfl_xor(sQ, 32);
            if(hi == 0){ red[(wv*16+lr)*2] = sS; red[(wv*16+lr)*2+1] = sQ; }
            __syncthreads();
            if(wv < 4 && ln < 16){
                float S = red[(wv*16+ln)*2]   + red[((wv+4)*16+ln)*2];
                float Q = red[(wv*16+ln)*2+1] + red[((wv+4)*16+ln)*2+1];
                int c2 = n0 + wv*32 + n*16 + ln;
                if(c2 < EMB){
                    atomicAdd(&stats[c2], S);
                    atomicAdd(&stats[EMB + c2], Q);
                }
            }
            __syncthreads();
        }
        if(EPI == 1){
            // ---- fp32 bounce in two 64-row halves (final layer, ldc=EMB) ---
            float* Cf = (float*)Cptr;
            float* Cs = (float*)smem_c;            // [64][132] = 33,792 B
            #pragma unroll
            for(int half=0; half<2; half++){
                if(wvm == half){
                    #pragma unroll
                    for(int n=0;n<2;n++){
                        int col = wvn*32 + n*16 + lr;
                        float bsv = (n0 + col < EMB) ? bias[n0 + col] : 0.f;
                        #pragma unroll
                        for(int m=0;m<4;m++){
                            #pragma unroll
                            for(int j=0;j<4;j++){
                                int rl = m*16 + hi*4 + j;      // 0..63
                                Cs[rl*132 + col] = acc[m][n][j] + bsv;
                            }
                        }
                    }
                }
                __syncthreads();
                #pragma unroll
                for(int i=0;i<4;i++){
                    int id = i*512 + tid;
                    int rr = id >> 5, c4 = id & 31;
                    int col = n0 + c4*4;
                    int gr = m0 + half*64 + rr;
                    if(col < EMB && gr < M)
                        *(float4*)(Cf + (size_t)gr*ldc + col) =
                            *(const float4*)(Cs + rr*132 + c4*4);
                }
                __syncthreads();
            }
        } else {
            // ---- EPI 2: bf16 bounce [128][136], col<300 mask (houtb) -------
            unsigned short* Cs = smem_u;           // [128][136] = 34,816 B
            unsigned short* Cb = (unsigned short*)Cptr;
            #pragma unroll
            for(int n=0;n<2;n++){
                int col = wvn*32 + n*16 + lr;
                int gcol = n0 + col;
                bool cok = (gcol < EMB);
                float bsv = cok ? bias[gcol] : 0.f;
                #pragma unroll
                for(int m=0;m<4;m++){
                    #pragma unroll
                    for(int j=0;j<4;j++){
                        int row = wvm*64 + m*16 + hi*4 + j;
                        Cs[row*136 + col] =
                            cok ? f2bf(acc[m][n][j] + bsv) : (unsigned short)0;
                    }
                }
            }
            __syncthreads();
            #pragma unroll
            for(int i=0;i<4;i++){
                int id = i*512 + tid;
                int rr = id >> 4, ch = id & 15;
                int gr = m0 + rr;
                int gc = n0 + ch*8;
                if(gr < M && gc < HB)
                    *(short8*)(Cb + (size_t)gr*ldc + gc) =
                        *(const short8*)(Cs + rr*136 + ch*8);
            }
        }
    }
}

// ---------------- BN apply (final layer only: no relu, writes dout) ---------
__global__ void k_bnapply(const float* __restrict__ X, const float* __restrict__ stats,
                          const float* __restrict__ g, const float* __restrict__ bt,
                          float* __restrict__ dout){
    int idx = blockIdx.x*blockDim.x + threadIdx.x;
    if(idx >= N_NODESC*75) return;
    int i = idx / 75, c = idx % 75;
    const float4* X4 = (const float4*)X;
    float4 v  = X4[(size_t)i*75 + c];
    float4 s  = ((const float4*)stats)[c];
    float4 q  = ((const float4*)stats)[75 + c];
    float4 gg = ((const float4*)g)[c];
    float4 bb = ((const float4*)bt)[c];
    const float inv_n = 1.0f/(float)N_NODESC;
    #define BN1(f) { float m = s.f*inv_n; float var = q.f*inv_n - m*m;          \
                     float r = rsqrtf(var + BN_EPS);                             \
                     v.f = (v.f - m)*r*gg.f + bb.f; }
    BN1(x) BN1(y) BN1(z) BN1(w)
    #undef BN1
    ((float4*)dout)[(size_t)i*75 + c] = v;
}

// ----------------------------------------------------------------------------
extern "C" void kernel_launch(void* const* d_in, const int* in_sizes, int n_in,
                              void* d_out, int out_size, void* d_ws, size_t ws_size,
                              hipStream_t stream) {
    const int*   x     = (const int*)d_in[0];
    const int*   ei    = (const int*)d_in[1];
    const int*   ea    = (const int*)d_in[2];
    const float* aemb1 = (const float*)d_in[3];
    const float* aemb2 = (const float*)d_in[4];
    const float* eemb1 = (const float*)d_in[5];
    const float* eemb2 = (const float*)d_in[6];
    const float* W1    = (const float*)d_in[7];
    const float* b1    = (const float*)d_in[8];
    const float* W2    = (const float*)d_in[9];
    const float* b2    = (const float*)d_in[10];
    const float* gamma = (const float*)d_in[11];
    const float* beta  = (const float*)d_in[12];
    float* dout = (float*)d_out;

    // workspace layout
    float* h      = (float*)d_ws;                              // 100000*304 f
    float* bias1p = h + (size_t)N_NODESC*LD;                   // 5*640 f
    float* etab   = bias1p + LAYERS*N1;                        // 5*18*304 f
    float* stats  = etab + LAYERS*18*LD;                       // 640 f
    float* aff    = stats + 640;                               // 640 f
    unsigned short* agg   = (unsigned short*)(aff + 640);      // 100000*320 bf16
    unsigned short* hmid  = agg  + (size_t)N_NODESC*K1;        // 100000*640 bf16
    unsigned short* houtb = hmid + (size_t)N_NODESC*N1;        // 100000*320 bf16
    unsigned short* wb1t  = houtb + (size_t)N_NODESC*HB;       // 5*640*320 bf16
    unsigned short* wb2t  = wb1t + (size_t)LAYERS*N1*K1;       // 5*384*640 bf16
    int*   deg     = (int*)(wb2t + (size_t)LAYERS*N2*K2);
    int*   offs    = deg    + N_NODESC;
    int*   cursor  = offs   + N_NODESC + 1;
    int*   csr_src = cursor + N_NODESC + 1;
    int*   csr_ea  = csr_src + N_EDGESC;
    int*   bsum    = csr_ea + N_EDGESC;
    int*   bpre    = bsum + NB_SCAN;

    const int nb_nf4 = (N_NODESC*LD4 + 255)/256;

    // one-time setup
    k_atom<<<nb_nf4, 256, 0, stream>>>(x, aemb1, aemb2, h);
    k_etab<<<(LAYERS*18*LD4 + 255)/256, 256, 0, stream>>>(eemb1, eemb2, etab);
    k_prepw1<<<(LAYERS*N1*K1 + 255)/256, 256, 0, stream>>>(W1, wb1t);
    k_prepw2<<<(LAYERS*N2*K2 + 255)/256, 256, 0, stream>>>(W2, wb2t);
    k_prepb1<<<(LAYERS*N1 + 255)/256, 256, 0, stream>>>(b1, bias1p);
    k_zero_i<<<(N_NODESC + 255)/256, 256, 0, stream>>>(deg, N_NODESC);
    k_deg<<<(N_EDGESC + 255)/256, 256, 0, stream>>>(ei, deg);
    k_bsum<<<NB_SCAN, 256, 0, stream>>>(deg, bsum);
    k_bscan<<<1, 512, 0, stream>>>(bsum, bpre, offs);
    k_offs<<<NB_SCAN, 256, 0, stream>>>(deg, bpre, offs, cursor);
    k_fill<<<(N_EDGESC + 255)/256, 256, 0, stream>>>(ei, ea, cursor, csr_src, csr_ea);

    const int MT = (N_NODESC + 127)/128;   // 782 M-tiles of 128 rows
    const int nwg1 = 5*MT, nwg2 = 3*MT;
    for(int l=0; l<LAYERS; l++){
        if(l == 0)
            k_agg0<<<(N_NODESC*80 + 255)/256, 256, 0, stream>>>(
                h, etab, offs, csr_src, csr_ea, agg);
        else
            k_aggB<<<(N_NODESC*40 + 255)/256, 256, 0, stream>>>(
                houtb, etab + (size_t)l*18*LD, aff, offs, csr_src, csr_ea, agg);
        k_zero_f<<<(2*EMB + 255)/256, 256, 0, stream>>>(stats, 2*EMB);
        k_mgemm<0, 10, 5><<<nwg1, 512, 0, stream>>>(
            agg, wb1t + (size_t)l*N1*K1, bias1p + (size_t)l*N1,
            hmid, N_NODESC, N1, nullptr, nwg1);
        if(l < LAYERS-1){
            k_mgemm<2, 20, 3><<<nwg2, 512, 0, stream>>>(
                hmid, wb2t + (size_t)l*N2*K2, b2 + (size_t)l*EMB,
                houtb, N_NODESC, HB, stats, nwg2);
            k_bnaff<<<2, 256, 0, stream>>>(stats, gamma + (size_t)l*EMB,
                                           beta + (size_t)l*EMB, aff);
        } else {
            k_mgemm<1, 20, 3><<<nwg2, 512, 0, stream>>>(
                hmid, wb2t + (size_t)l*N2*K2, b2 + (size_t)l*EMB,
                dout, N_NODESC, EMB, stats, nwg2);
            k_bnapply<<<(N_NODESC*75 + 255)/256, 256, 0, stream>>>(
                dout, stats, gamma + (size_t)l*EMB, beta + (size_t)l*EMB, dout);
        }
    }
}

// Round 12
// 1164.516 us; speedup vs baseline: 1.2687x; 1.2256x over previous
//
#include <hip/hip_runtime.h>
#include <hip/hip_bf16.h>

#define N_NODESC 100000
#define N_EDGESC 250000
#define EMB 300
#define LD 304      // fp32 h / etab stride (float4-friendly)
#define LD4 76
#define LAYERS 5
#define BN_EPS 1e-5f

#define K1 320      // padded K for GEMM1 (agg stride)
#define N1 640      // padded N for GEMM1 (hmid stride, = K for GEMM2)
#define K2 640
#define N2 384      // padded N for GEMM2 (output guarded to 300)
#define HB 320      // houtb stride (bf16 intermediate hout)

#define NB_SCAN 391 // ceil(100000/256)

typedef __attribute__((ext_vector_type(8))) short short8;
typedef __attribute__((ext_vector_type(4))) float f32x4;

#define GLOAD16(g, l) __builtin_amdgcn_global_load_lds( \
    (const __attribute__((address_space(1))) void*)(g), \
    (__attribute__((address_space(3))) void*)(l), 16, 0, 0)

__device__ __forceinline__ float4 f4add(float4 a, float4 b){
    return make_float4(a.x+b.x, a.y+b.y, a.z+b.z, a.w+b.w);
}
__device__ __forceinline__ unsigned short f2bf(float f){
    __hip_bfloat16 h = __float2bfloat16(f);
    return *(unsigned short*)&h;
}
__device__ __forceinline__ float bf2f(unsigned short u){
    unsigned int x = ((unsigned int)u) << 16;
    union { unsigned int i; float f; } c; c.i = x; return c.f;
}

// ---------------- utility zero kernels --------------------------------------
__global__ void k_zero_i(int* p, int n){
    int i = blockIdx.x*blockDim.x + threadIdx.x;
    if(i < n) p[i] = 0;
}
__global__ void k_zero_f(float* p, int n){
    int i = blockIdx.x*blockDim.x + threadIdx.x;
    if(i < n) p[i] = 0.f;
}

// ---------------- atom encoder: h = emb1[x0] + emb2[x1], fp32 stride LD -----
__global__ void k_atom(const int* __restrict__ x,
                       const float* __restrict__ e1,
                       const float* __restrict__ e2,
                       float* __restrict__ h){
    int idx = blockIdx.x*blockDim.x + threadIdx.x;
    if(idx >= N_NODESC*LD4) return;
    int i = idx / LD4, c = idx % LD4;
    float4 v = make_float4(0,0,0,0);
    if(c < 75){
        int i0 = x[2*i], i1 = x[2*i+1];
        const float4* r1 = (const float4*)(e1 + (size_t)i0*EMB);
        const float4* r2 = (const float4*)(e2 + (size_t)i1*EMB);
        v = f4add(r1[c], r2[c]);
    }
    ((float4*)h)[idx] = v;
}

// ---------------- combined edge-embedding table etab[l][ea0*3+ea1][LD] ------
__global__ void k_etab(const float* __restrict__ e1,
                       const float* __restrict__ e2,
                       float* __restrict__ etab){
    int idx = blockIdx.x*blockDim.x + threadIdx.x;
    if(idx >= LAYERS*18*LD4) return;
    int l = idx / (18*LD4);
    int r = idx % (18*LD4);
    int c = r / LD4, f = r % LD4;
    float4 v = make_float4(0,0,0,0);
    if(f < 75){
        const float4* r1 = (const float4*)(e1 + (size_t)(l*6 + c/3)*EMB);
        const float4* r2 = (const float4*)(e2 + (size_t)(l*3 + c%3)*EMB);
        v = f4add(r1[f], r2[f]);
    }
    ((float4*)etab)[idx] = v;
}

// ---------------- weight prep: B^T padded bf16 ------------------------------
__global__ void k_prepw1(const float* __restrict__ W1, unsigned short* __restrict__ wb){
    int idx = blockIdx.x*blockDim.x + threadIdx.x;
    if(idx >= LAYERS*N1*K1) return;
    int l = idx / (N1*K1);
    int r = idx % (N1*K1);
    int n = r / K1, k = r % K1;
    float v = (n < 600 && k < EMB) ? W1[((size_t)l*EMB + k)*600 + n] : 0.f;
    wb[idx] = f2bf(v);
}
__global__ void k_prepw2(const float* __restrict__ W2, unsigned short* __restrict__ wb){
    int idx = blockIdx.x*blockDim.x + threadIdx.x;
    if(idx >= LAYERS*N2*K2) return;
    int l = idx / (N2*K2);
    int r = idx % (N2*K2);
    int n = r / K2, k = r % K2;
    float v = (n < EMB && k < 600) ? W2[((size_t)l*600 + k)*EMB + n] : 0.f;
    wb[idx] = f2bf(v);
}
__global__ void k_prepb1(const float* __restrict__ b1, float* __restrict__ bp){
    int idx = blockIdx.x*blockDim.x + threadIdx.x;
    if(idx >= LAYERS*N1) return;
    int l = idx / N1, n = idx % N1;
    bp[idx] = (n < 600) ? b1[(size_t)l*600 + n] : 0.f;
}

// ---------------- CSR build -------------------------------------------------
__global__ void k_deg(const int* __restrict__ ei, int* __restrict__ deg){
    int e = blockIdx.x*blockDim.x + threadIdx.x;
    if(e >= N_EDGESC) return;
    atomicAdd(&deg[ei[N_EDGESC + e]], 1);
}

__global__ void k_bsum(const int* __restrict__ deg, int* __restrict__ bsum){
    int g = blockIdx.x*256 + threadIdx.x;
    int v = (g < N_NODESC) ? deg[g] : 0;
    #pragma unroll
    for(int o=32;o>0;o>>=1) v += __shfl_down(v, o);
    __shared__ int sw[4];
    if((threadIdx.x & 63) == 0) sw[threadIdx.x>>6] = v;
    __syncthreads();
    if(threadIdx.x == 0) bsum[blockIdx.x] = sw[0]+sw[1]+sw[2]+sw[3];
}

__global__ void k_bscan(const int* __restrict__ bsum, int* __restrict__ bpre,
                        int* __restrict__ offs){
    __shared__ int sh[512];
    int t = threadIdx.x;
    int v = (t < NB_SCAN) ? bsum[t] : 0;
    sh[t] = v; __syncthreads();
    for(int o=1;o<512;o<<=1){
        int u = (t >= o) ? sh[t-o] : 0;
        __syncthreads();
        sh[t] += u;
        __syncthreads();
    }
    if(t < NB_SCAN) bpre[t] = sh[t] - v;
    if(t == NB_SCAN-1) offs[N_NODESC] = sh[t];
}

__global__ void k_offs(const int* __restrict__ deg, const int* __restrict__ bpre,
                       int* __restrict__ offs, int* __restrict__ cursor){
    __shared__ int sh[256];
    int t = threadIdx.x;
    int g = blockIdx.x*256 + t;
    int v = (g < N_NODESC) ? deg[g] : 0;
    sh[t] = v; __syncthreads();
    for(int o=1;o<256;o<<=1){
        int u = (t >= o) ? sh[t-o] : 0;
        __syncthreads();
        sh[t] += u;
        __syncthreads();
    }
    if(g < N_NODESC){
        int e = bpre[blockIdx.x] + sh[t] - v;
        offs[g] = e; cursor[g] = e;
    }
}

__global__ void k_fill(const int* __restrict__ ei, const int* __restrict__ ea,
                       int* __restrict__ cursor,
                       int* __restrict__ csr_src, int* __restrict__ csr_ea){
    int e = blockIdx.x*blockDim.x + threadIdx.x;
    if(e >= N_EDGESC) return;
    int d = ei[N_EDGESC + e];
    int p = atomicAdd(&cursor[d], 1);
    csr_src[p] = ei[e];
    csr_ea[p]  = ea[2*e]*3 + ea[2*e+1];
}

// ---------------- layer-0 gather (fp32 h source) ----------------------------
__global__ void k_agg0(const float* __restrict__ h, const float* __restrict__ etab_l,
                       const int* __restrict__ offs, const int* __restrict__ csr_src,
                       const int* __restrict__ csr_ea, unsigned short* __restrict__ agg){
    int idx = blockIdx.x*blockDim.x + threadIdx.x;
    if(idx >= N_NODESC*80) return;
    int i = idx / 80, c = idx % 80;
    ushort4 out;
    if(c < 75){
        const float4* h4 = (const float4*)h;
        const float4* et = (const float4*)etab_l;
        float4 acc = f4add(h4[(size_t)i*LD4 + c], et[12*LD4 + c]);
        int j0 = offs[i], j1 = offs[i+1];
        for(int j=j0; j<j1; j++){
            int s = csr_src[j];
            int t = csr_ea[j];
            acc = f4add(acc, f4add(h4[(size_t)s*LD4 + c], et[t*LD4 + c]));
        }
        out.x = f2bf(acc.x); out.y = f2bf(acc.y);
        out.z = f2bf(acc.z); out.w = f2bf(acc.w);
    } else {
        out.x = out.y = out.z = out.w = 0;
    }
    *(ushort4*)(agg + (size_t)i*K1 + c*4) = out;
}

// ---------------- layers 1-4 gather (bf16 houtb source + BN affine) ---------
// R8-aggT shape restored (R11 lesson: 40 chunks/node halved the TLP that
// hides the serial edge-loop latency, and 8 scalar etab loads per edge
// replaced one float4 — 142 µs vs ~60).  80 chunks/node, 4 cols each:
// ushort4 (8B) gather load + float4 etab load + 4-wide fma/max in fp32.
__global__ void k_aggB(const unsigned short* __restrict__ src,
                       const float* __restrict__ etab_l,
                       const float* __restrict__ aff,
                       const int* __restrict__ offs, const int* __restrict__ csr_src,
                       const int* __restrict__ csr_ea, unsigned short* __restrict__ agg){
    int idx = blockIdx.x*blockDim.x + threadIdx.x;
    if(idx >= N_NODESC*80) return;
    int i = idx / 80, c = idx % 80;
    ushort4 out;
    if(c < 75){
        const float4* et = (const float4*)etab_l;
        float4 a4 = ((const float4*)aff)[c];
        float4 b4 = ((const float4*)aff)[75 + c];
        ushort4 sv = *(const ushort4*)(src + (size_t)i*HB + c*4);
        float4 e12 = et[12*LD4 + c];
        float4 acc;
        acc.x = fmaxf(fmaf(bf2f(sv.x), a4.x, b4.x), 0.f) + e12.x;
        acc.y = fmaxf(fmaf(bf2f(sv.y), a4.y, b4.y), 0.f) + e12.y;
        acc.z = fmaxf(fmaf(bf2f(sv.z), a4.z, b4.z), 0.f) + e12.z;
        acc.w = fmaxf(fmaf(bf2f(sv.w), a4.w, b4.w), 0.f) + e12.w;
        int j0 = offs[i], j1 = offs[i+1];
        for(int j=j0; j<j1; j++){
            int s = csr_src[j];
            int t = csr_ea[j];
            ushort4 nv = *(const ushort4*)(src + (size_t)s*HB + c*4);
            float4 ev = et[t*LD4 + c];
            acc.x += fmaxf(fmaf(bf2f(nv.x), a4.x, b4.x), 0.f) + ev.x;
            acc.y += fmaxf(fmaf(bf2f(nv.y), a4.y, b4.y), 0.f) + ev.y;
            acc.z += fmaxf(fmaf(bf2f(nv.z), a4.z, b4.z), 0.f) + ev.z;
            acc.w += fmaxf(fmaf(bf2f(nv.w), a4.w, b4.w), 0.f) + ev.w;
        }
        out.x = f2bf(acc.x); out.y = f2bf(acc.y);
        out.z = f2bf(acc.z); out.w = f2bf(acc.w);
    } else {
        out.x = out.y = out.z = out.w = 0;
    }
    *(ushort4*)(agg + (size_t)i*K1 + c*4) = out;
}

// ---------------- BN affine precompute: a = g*rsqrt(var+eps), b = bt - m*a --
__global__ void k_bnaff(const float* __restrict__ stats, const float* __restrict__ g,
                        const float* __restrict__ bt, float* __restrict__ aff){
    int c = blockIdx.x*blockDim.x + threadIdx.x;
    if(c >= EMB) return;
    const float inv_n = 1.0f/(float)N_NODESC;
    float m = stats[c]*inv_n;
    float var = stats[EMB + c]*inv_n - m*m;
    float a = g[c]*rsqrtf(var + BN_EPS);
    aff[c] = a;
    aff[EMB + c] = bt[c] - m*a;
}

// ---------------- bf16 MFMA GEMM: C = epi(A @ Bt^T + bias) ------------------
// EXACT R8 shell (proven best): 128x128 tile, 512 threads, 8 waves (2M x 4N,
// wave tile 64x32), BK=32, 3-buffer LDS + counted-vmcnt pipeline; per step
// {vmcnt(2) lgkmcnt(0); s_barrier; SB(0); STAGE(kc+2); ds_read; setprio(1);
//  8 MFMA; setprio(0)}. vmcnt(0) only last.  Prologue STAGEs fenced (R6).
// Chunk-swizzle ^((row>>1)&3) both sides.
// EPI 0: bf16 LDS-bounce [128][144] store, +bias, relu (hmid, ldc=N1).
// EPI 1: fp32 stats + fp32 LDS-bounce halves [64][132] (final dout, ldc=EMB).
// EPI 2: fp32 stats + bf16 LDS-bounce [128][136], col<300 mask (houtb, ldc=HB).
template<int EPI, int KS, int NX>
__global__ __launch_bounds__(512) void k_mgemm(
    const unsigned short* __restrict__ A,
    const unsigned short* __restrict__ Bt,
    const float* __restrict__ bias,
    void* __restrict__ Cptr, int M, int ldc,
    float* __restrict__ stats, int nwg)
{
    __shared__ char smem_c[3*16384 + 1024];    // 3 bufs (A 8K | B 8K) + red
    unsigned short* smem_u = (unsigned short*)smem_c;

    // ---- XCD bijective remap, x-major decomposition ------------------------
    int bid = blockIdx.x;
    int q = nwg >> 3, r = nwg & 7;
    int xcd = bid & 7, lo = bid >> 3;
    int wg = (xcd < r) ? (xcd*(q+1) + lo) : (r*(q+1) + (xcd - r)*q + lo);
    int bx = wg % NX, by = wg / NX;
    int m0 = by*128, n0 = bx*128;

    const int tid = threadIdx.x;
    const int wv = tid >> 6, ln = tid & 63;
    const int wvm = wv >> 2, wvn = wv & 3;     // wave tile: rows wvm*64, cols wvn*32
    const int lr = ln & 15, hi = ln >> 4;

    // ---- staging: 1 chunk of A + 1 of B per thread per tile ----------------
    const int rS = tid >> 2, cS = tid & 3;     // row 0..127, phys chunk 0..3
    int gA = m0 + rS; if(gA >= M) gA = M-1;
    const unsigned short* srcA = A  + (size_t)gA*(KS*32)        + ((cS ^ ((rS>>1)&3))<<3);
    const unsigned short* srcB = Bt + (size_t)(n0 + rS)*(KS*32) + ((cS ^ ((rS>>1)&3))<<3);

    f32x4 acc[4][2] = {};

    // stage tile t into buf t%3 (2 loads/thread -> vmcnt counts 2 per tile)
    #define STAGE(t) { \
        char* db_ = smem_c + ((t)%3)*16384; \
        GLOAD16(srcA + (t)*32, db_ + tid*16); \
        GLOAD16(srcB + (t)*32, db_ + 8192 + tid*16); }

    // ---- prologue: tiles 0,1 — fenced so issue order matches vmcnt ---------
    STAGE(0)
    __builtin_amdgcn_sched_barrier(0);
    STAGE(1)
    __builtin_amdgcn_sched_barrier(0);

    // per-lane ds_read offsets (ushort units), row-constant across kc
    int offA[4], offB[2];
    #pragma unroll
    for(int m=0;m<4;m++){
        int row = wvm*64 + m*16 + lr;
        offA[m] = row*32 + ((hi ^ ((row>>1)&3))<<3);
    }
    #pragma unroll
    for(int n=0;n<2;n++){
        int brow = wvn*32 + n*16 + lr;
        offB[n] = 4096 + brow*32 + ((hi ^ ((brow>>1)&3))<<3);
    }

    #pragma unroll
    for(int kc=0; kc<KS; kc++){
        // wait for tile kc (allow tile kc+1's 2 loads to stay in flight)
        if(kc == KS-1) asm volatile("s_waitcnt vmcnt(0) lgkmcnt(0)" ::: "memory");
        else           asm volatile("s_waitcnt vmcnt(2) lgkmcnt(0)" ::: "memory");
        __builtin_amdgcn_s_barrier();
        __builtin_amdgcn_sched_barrier(0);   // keep STAGE strictly after barrier
        if(kc+2 < KS) STAGE(kc+2)
        const unsigned short* bufu = smem_u + (kc%3)*8192;
        short8 av[4], bv[2];
        #pragma unroll
        for(int m=0;m<4;m++) av[m] = *(const short8*)(bufu + offA[m]);
        #pragma unroll
        for(int n=0;n<2;n++) bv[n] = *(const short8*)(bufu + offB[n]);
        __builtin_amdgcn_s_setprio(1);
        #pragma unroll
        for(int m=0;m<4;m++)
            #pragma unroll
            for(int n=0;n<2;n++)
                acc[m][n] = __builtin_amdgcn_mfma_f32_16x16x32_bf16(
                                av[m], bv[n], acc[m][n], 0, 0, 0);
        __builtin_amdgcn_s_setprio(0);
    }
    #undef STAGE

    __syncthreads();   // full drain; LDS free for epilogue reuse

    if(EPI == 0){
        // ---- bounce C tile (bf16) through LDS (stride 144), short8 stores --
        unsigned short* Cs = smem_u;          // [128][144] = 36,864 B
        unsigned short* Cb = (unsigned short*)Cptr;
        #pragma unroll
        for(int n=0;n<2;n++){
            int col = wvn*32 + n*16 + lr;
            float bsv = bias[n0 + col];
            #pragma unroll
            for(int m=0;m<4;m++){
                #pragma unroll
                for(int j=0;j<4;j++){
                    int row = wvm*64 + m*16 + hi*4 + j;
                    Cs[row*144 + col] = f2bf(fmaxf(acc[m][n][j] + bsv, 0.f));
                }
            }
        }
        __syncthreads();
        #pragma unroll
        for(int i=0;i<4;i++){
            int id = i*512 + tid;
            int rr = id >> 4, ch = id & 15;
            int gr = m0 + rr;
            if(gr < M)
                *(short8*)(Cb + (size_t)gr*ldc + n0 + ch*8) =
                    *(const short8*)(Cs + rr*144 + ch*8);
        }
    } else {
        // ---- fused BN stats (identical for EPI 1/2): from fp32 acc ---------
        float* red = (float*)(smem_c + 3*16384);   // 256 floats
        #pragma unroll
        for(int n=0;n<2;n++){
            int col = n0 + wvn*32 + n*16 + lr;
            bool cok = (col < EMB);
            float bsv = cok ? bias[col] : 0.f;
            float sS = 0.f, sQ = 0.f;
            #pragma unroll
            for(int m=0;m<4;m++){
                #pragma unroll
                for(int j=0;j<4;j++){
                    int row = m0 + wvm*64 + m*16 + hi*4 + j;
                    if(cok && row < M){
                        float v = acc[m][n][j] + bsv;
                        sS += v; sQ += v*v;
                    }
                }
            }
            sS += __shfl_xor(sS, 16); sQ += __shfl_xor(sQ, 16);
            sS += __shfl_xor(sS, 32); sQ += __shfl_xor(sQ, 32);
            if(hi == 0){ red[(wv*16+lr)*2] = sS; red[(wv*16+lr)*2+1] = sQ; }
            __syncthreads();
            if(wv < 4 && ln < 16){
                float S = red[(wv*16+ln)*2]   + red[((wv+4)*16+ln)*2];
                float Q = red[(wv*16+ln)*2+1] + red[((wv+4)*16+ln)*2+1];
                int c2 = n0 + wv*32 + n*16 + ln;
                if(c2 < EMB){
                    atomicAdd(&stats[c2], S);
                    atomicAdd(&stats[EMB + c2], Q);
                }
            }
            __syncthreads();
        }
        if(EPI == 1){
            // ---- fp32 bounce in two 64-row halves (final layer, ldc=EMB) ---
            float* Cf = (float*)Cptr;
            float* Cs = (float*)smem_c;            // [64][132] = 33,792 B
            #pragma unroll
            for(int half=0; half<2; half++){
                if(wvm == half){
                    #pragma unroll
                    for(int n=0;n<2;n++){
                        int col = wvn*32 + n*16 + lr;
                        float bsv = (n0 + col < EMB) ? bias[n0 + col] : 0.f;
                        #pragma unroll
                        for(int m=0;m<4;m++){
                            #pragma unroll
                            for(int j=0;j<4;j++){
                                int rl = m*16 + hi*4 + j;      // 0..63
                                Cs[rl*132 + col] = acc[m][n][j] + bsv;
                            }
                        }
                    }
                }
                __syncthreads();
                #pragma unroll
                for(int i=0;i<4;i++){
                    int id = i*512 + tid;
                    int rr = id >> 5, c4 = id & 31;
                    int col = n0 + c4*4;
                    int gr = m0 + half*64 + rr;
                    if(col < EMB && gr < M)
                        *(float4*)(Cf + (size_t)gr*ldc + col) =
                            *(const float4*)(Cs + rr*132 + c4*4);
                }
                __syncthreads();
            }
        } else {
            // ---- EPI 2: bf16 bounce [128][136], col<300 mask (houtb) -------
            unsigned short* Cs = smem_u;           // [128][136] = 34,816 B
            unsigned short* Cb = (unsigned short*)Cptr;
            #pragma unroll
            for(int n=0;n<2;n++){
                int col = wvn*32 + n*16 + lr;
                int gcol = n0 + col;
                bool cok = (gcol < EMB);
                float bsv = cok ? bias[gcol] : 0.f;
                #pragma unroll
                for(int m=0;m<4;m++){
                    #pragma unroll
                    for(int j=0;j<4;j++){
                        int row = wvm*64 + m*16 + hi*4 + j;
                        Cs[row*136 + col] =
                            cok ? f2bf(acc[m][n][j] + bsv) : (unsigned short)0;
                    }
                }
            }
            __syncthreads();
            #pragma unroll
            for(int i=0;i<4;i++){
                int id = i*512 + tid;
                int rr = id >> 4, ch = id & 15;
                int gr = m0 + rr;
                int gc = n0 + ch*8;
                if(gr < M && gc < HB)
                    *(short8*)(Cb + (size_t)gr*ldc + gc) =
                        *(const short8*)(Cs + rr*136 + ch*8);
            }
        }
    }
}

// ---------------- BN apply (final layer only: no relu, writes dout) ---------
__global__ void k_bnapply(const float* __restrict__ X, const float* __restrict__ stats,
                          const float* __restrict__ g, const float* __restrict__ bt,
                          float* __restrict__ dout){
    int idx = blockIdx.x*blockDim.x + threadIdx.x;
    if(idx >= N_NODESC*75) return;
    int i = idx / 75, c = idx % 75;
    const float4* X4 = (const float4*)X;
    float4 v  = X4[(size_t)i*75 + c];
    float4 s  = ((const float4*)stats)[c];
    float4 q  = ((const float4*)stats)[75 + c];
    float4 gg = ((const float4*)g)[c];
    float4 bb = ((const float4*)bt)[c];
    const float inv_n = 1.0f/(float)N_NODESC;
    #define BN1(f) { float m = s.f*inv_n; float var = q.f*inv_n - m*m;          \
                     float r = rsqrtf(var + BN_EPS);                             \
                     v.f = (v.f - m)*r*gg.f + bb.f; }
    BN1(x) BN1(y) BN1(z) BN1(w)
    #undef BN1
    ((float4*)dout)[(size_t)i*75 + c] = v;
}

// ----------------------------------------------------------------------------
extern "C" void kernel_launch(void* const* d_in, const int* in_sizes, int n_in,
                              void* d_out, int out_size, void* d_ws, size_t ws_size,
                              hipStream_t stream) {
    const int*   x     = (const int*)d_in[0];
    const int*   ei    = (const int*)d_in[1];
    const int*   ea    = (const int*)d_in[2];
    const float* aemb1 = (const float*)d_in[3];
    const float* aemb2 = (const float*)d_in[4];
    const float* eemb1 = (const float*)d_in[5];
    const float* eemb2 = (const float*)d_in[6];
    const float* W1    = (const float*)d_in[7];
    const float* b1    = (const float*)d_in[8];
    const float* W2    = (const float*)d_in[9];
    const float* b2    = (const float*)d_in[10];
    const float* gamma = (const float*)d_in[11];
    const float* beta  = (const float*)d_in[12];
    float* dout = (float*)d_out;

    // workspace layout
    float* h      = (float*)d_ws;                              // 100000*304 f
    float* bias1p = h + (size_t)N_NODESC*LD;                   // 5*640 f
    float* etab   = bias1p + LAYERS*N1;                        // 5*18*304 f
    float* stats  = etab + LAYERS*18*LD;                       // 640 f
    float* aff    = stats + 640;                               // 640 f
    unsigned short* agg   = (unsigned short*)(aff + 640);      // 100000*320 bf16
    unsigned short* hmid  = agg  + (size_t)N_NODESC*K1;        // 100000*640 bf16
    unsigned short* houtb = hmid + (size_t)N_NODESC*N1;        // 100000*320 bf16
    unsigned short* wb1t  = houtb + (size_t)N_NODESC*HB;       // 5*640*320 bf16
    unsigned short* wb2t  = wb1t + (size_t)LAYERS*N1*K1;       // 5*384*640 bf16
    int*   deg     = (int*)(wb2t + (size_t)LAYERS*N2*K2);
    int*   offs    = deg    + N_NODESC;
    int*   cursor  = offs   + N_NODESC + 1;
    int*   csr_src = cursor + N_NODESC + 1;
    int*   csr_ea  = csr_src + N_EDGESC;
    int*   bsum    = csr_ea + N_EDGESC;
    int*   bpre    = bsum + NB_SCAN;

    const int nb_nf4 = (N_NODESC*LD4 + 255)/256;

    // one-time setup
    k_atom<<<nb_nf4, 256, 0, stream>>>(x, aemb1, aemb2, h);
    k_etab<<<(LAYERS*18*LD4 + 255)/256, 256, 0, stream>>>(eemb1, eemb2, etab);
    k_prepw1<<<(LAYERS*N1*K1 + 255)/256, 256, 0, stream>>>(W1, wb1t);
    k_prepw2<<<(LAYERS*N2*K2 + 255)/256, 256, 0, stream>>>(W2, wb2t);
    k_prepb1<<<(LAYERS*N1 + 255)/256, 256, 0, stream>>>(b1, bias1p);
    k_zero_i<<<(N_NODESC + 255)/256, 256, 0, stream>>>(deg, N_NODESC);
    k_deg<<<(N_EDGESC + 255)/256, 256, 0, stream>>>(ei, deg);
    k_bsum<<<NB_SCAN, 256, 0, stream>>>(deg, bsum);
    k_bscan<<<1, 512, 0, stream>>>(bsum, bpre, offs);
    k_offs<<<NB_SCAN, 256, 0, stream>>>(deg, bpre, offs, cursor);
    k_fill<<<(N_EDGESC + 255)/256, 256, 0, stream>>>(ei, ea, cursor, csr_src, csr_ea);

    const int MT = (N_NODESC + 127)/128;   // 782 M-tiles of 128 rows
    const int nwg1 = 5*MT, nwg2 = 3*MT;
    const int nb_agg = (N_NODESC*80 + 255)/256;
    for(int l=0; l<LAYERS; l++){
        if(l == 0)
            k_agg0<<<nb_agg, 256, 0, stream>>>(
                h, etab, offs, csr_src, csr_ea, agg);
        else
            k_aggB<<<nb_agg, 256, 0, stream>>>(
                houtb, etab + (size_t)l*18*LD, aff, offs, csr_src, csr_ea, agg);
        k_zero_f<<<(2*EMB + 255)/256, 256, 0, stream>>>(stats, 2*EMB);
        k_mgemm<0, 10, 5><<<nwg1, 512, 0, stream>>>(
            agg, wb1t + (size_t)l*N1*K1, bias1p + (size_t)l*N1,
            hmid, N_NODESC, N1, nullptr, nwg1);
        if(l < LAYERS-1){
            k_mgemm<2, 20, 3><<<nwg2, 512, 0, stream>>>(
                hmid, wb2t + (size_t)l*N2*K2, b2 + (size_t)l*EMB,
                houtb, N_NODESC, HB, stats, nwg2);
            k_bnaff<<<2, 256, 0, stream>>>(stats, gamma + (size_t)l*EMB,
                                           beta + (size_t)l*EMB, aff);
        } else {
            k_mgemm<1, 20, 3><<<nwg2, 512, 0, stream>>>(
                hmid, wb2t + (size_t)l*N2*K2, b2 + (size_t)l*EMB,
                dout, N_NODESC, EMB, stats, nwg2);
            k_bnapply<<<(N_NODESC*75 + 255)/256, 256, 0, stream>>>(
                dout, stats, gamma + (size_t)l*EMB, beta + (size_t)l*EMB, dout);
        }
    }
}